// Round 4
// baseline (403.261 us; speedup 1.0000x reference)
//
#include <hip/hip_runtime.h>
#include <hip/hip_bf16.h>

#define NN 8192
#define FIN 128
#define FOUT 64
#define ALPHA 0.2f
#define BM 64                // rows per attn block
#define CHUNK 128            // j-tile per pipeline stage
#define SPLIT 8              // j-range split factor (1024 j per block)
#define JSLICE (NN / SPLIT)
#define NCHUNK (JSLICE / CHUNK)
#define PROW (CHUNK + 8)     // 272B row stride: 4-bank skew, b128 reads at min cycles

typedef __attribute__((ext_vector_type(8))) short short8;   // 8 bf16 (4 VGPRs)
typedef __attribute__((ext_vector_type(4))) float floatx4;

static __device__ __forceinline__ ushort f2bf(float f) {
    __hip_bfloat16 h = __float2bfloat16(f);
    return __builtin_bit_cast(ushort, h);
}

// K1: WhT[f][row] = bf16(x @ W); Wh1 = Wh@a[:64]; Wh2 = Wh@a[64:]  (fp32)
// grid NN/32 x 256: wave handles 8 rows; LDS transpose -> coalesced WhT stores.
__global__ __launch_bounds__(256) void gat_proj(const float* __restrict__ x,
                                                const float* __restrict__ W,
                                                const float* __restrict__ a,
                                                ushort* __restrict__ WhT,
                                                float* __restrict__ Wh1,
                                                float* __restrict__ Wh2) {
    __shared__ float tile[32][FOUT + 1];

    const int t = threadIdx.x;
    const int f = t & 63;
    const int wv = t >> 6;
    const int row0 = blockIdx.x * 32;
    const float af1 = a[f], af2 = a[FOUT + f];

    for (int r8 = 0; r8 < 8; ++r8) {
        const int row = row0 + wv * 8 + r8;
        const float4* __restrict__ x4 = (const float4*)(x + (size_t)row * FIN);
        float acc = 0.f;
        #pragma unroll
        for (int k4 = 0; k4 < FIN / 4; ++k4) {
            float4 xv = x4[k4];
            const int k = k4 * 4;
            acc = fmaf(xv.x, W[(k + 0) * FOUT + f], acc);
            acc = fmaf(xv.y, W[(k + 1) * FOUT + f], acc);
            acc = fmaf(xv.z, W[(k + 2) * FOUT + f], acc);
            acc = fmaf(xv.w, W[(k + 3) * FOUT + f], acc);
        }
        tile[wv * 8 + r8][f] = acc;

        float s1 = acc * af1;
        float s2 = acc * af2;
        #pragma unroll
        for (int off = 32; off; off >>= 1) {
            s1 += __shfl_xor(s1, off, 64);
            s2 += __shfl_xor(s2, off, 64);
        }
        if (f == 0) { Wh1[row] = s1; Wh2[row] = s2; }
    }
    __syncthreads();

    const int r = t & 31;
    const int fh = t >> 5;
    #pragma unroll
    for (int p = 0; p < 8; ++p) {
        const int ff = p * 8 + fh;
        WhT[(size_t)ff * NN + row0 + r] = f2bf(tile[r][ff]);
    }
}

// K2: partial masked-softmax numerator/denominator via bf16 MFMA.
// grid (NN/BM)*SPLIT = 1024 blocks x 256 threads (4 waves), 4 blocks/CU.
// Block (rowblk, slice): rows rowblk*64..+63, j in [slice*1024, +1024).
// Pipeline per chunk: load adj(c+1)->regs | MFMA(c) from LDS | scores(c+1)->LDS | sync.
// Phase A: wave wv scores rows wv*16..+15 (lane: jg=lane&31 covers 4 j, rh=lane>>5 picks row-half).
// Phase B: wave wv owns f-tile wv*16..+15; 4 m-tiles x 4 k-steps MFMA, B-frags reused x4.
__global__ __launch_bounds__(256) void gat_attn_part(const int* __restrict__ adj,
                                                     const ushort* __restrict__ WhT,
                                                     const float* __restrict__ Wh1,
                                                     const float* __restrict__ Wh2,
                                                     float* __restrict__ pnum,
                                                     float* __restrict__ pden) {
    __shared__ __align__(16) ushort P[2][BM][PROW];   // 34.8 KB

    const int t = threadIdx.x;
    const int lane = t & 63;
    const int wv = t >> 6;
    const int slice = blockIdx.x & (SPLIT - 1);
    const int row0 = (blockIdx.x / SPLIT) * BM;
    const int j0 = slice * JSLICE;
    const int ln = lane & 15;
    const int quad = lane >> 4;
    const int jg = lane & 31;      // j-group within chunk (4 j each)
    const int rh = lane >> 5;      // row half (0/1) within wave's 16 rows
    const int rbase = wv * 16;     // block-local first row of this wave's score rows

    // per-lane Wh1 for its 8 score rows (chunk-invariant)
    float wh1r[8];
    #pragma unroll
    for (int rr = 0; rr < 8; ++rr)
        wh1r[rr] = Wh1[row0 + rbase + rh * 8 + rr];

    const int* __restrict__ aptr =
        adj + (size_t)(row0 + rbase + rh * 8) * NN + j0 + jg * 4;

    int4 av[8];
    float4 wh2v;
    auto loadChunk = [&](int c) {              // issue VMEM only
        const int jb = c * CHUNK;
        wh2v = *(const float4*)(Wh2 + j0 + jb + jg * 4);
        #pragma unroll
        for (int rr = 0; rr < 8; ++rr)
            av[rr] = *(const int4*)(aptr + (size_t)rr * NN + jb);
    };

    float den[8];
    #pragma unroll
    for (int rr = 0; rr < 8; ++rr) den[rr] = 0.f;

    auto scoresToLds = [&](int b) {            // consume av/wh2v
        #pragma unroll
        for (int rr = 0; rr < 8; ++rr) {
            float s0 = wh1r[rr] + wh2v.x, s1 = wh1r[rr] + wh2v.y,
                  s2 = wh1r[rr] + wh2v.z, s3 = wh1r[rr] + wh2v.w;
            s0 = fmaxf(s0, ALPHA * s0); s1 = fmaxf(s1, ALPHA * s1);
            s2 = fmaxf(s2, ALPHA * s2); s3 = fmaxf(s3, ALPHA * s3);
            float p0 = __expf(s0), p1 = __expf(s1),
                  p2 = __expf(s2), p3 = __expf(s3);
            p0 = (av[rr].x > 0) ? p0 : 0.f; p1 = (av[rr].y > 0) ? p1 : 0.f;
            p2 = (av[rr].z > 0) ? p2 : 0.f; p3 = (av[rr].w > 0) ? p3 : 0.f;
            den[rr] += (p0 + p1) + (p2 + p3);
            ushort4 pk = make_ushort4(f2bf(p0), f2bf(p1), f2bf(p2), f2bf(p3));
            *(ushort4*)&P[b][rbase + rh * 8 + rr][jg * 4] = pk;
        }
    };

    floatx4 acc[4];
    #pragma unroll
    for (int mt = 0; mt < 4; ++mt) acc[mt] = (floatx4){0.f, 0.f, 0.f, 0.f};

    const ushort* __restrict__ bbase =
        WhT + (size_t)(wv * 16 + ln) * NN + j0 + quad * 8;

    loadChunk(0);
    scoresToLds(0);
    __syncthreads();

    int pb = 0;
    for (int c = 0; c < NCHUNK; ++c) {
        if (c + 1 < NCHUNK) loadChunk(c + 1);        // VMEM in flight across MFMA

        const int jb = c * CHUNK;
        short8 bf[4];
        #pragma unroll
        for (int k0 = 0; k0 < 4; ++k0)
            bf[k0] = *(const short8*)(bbase + jb + k0 * 32);
        #pragma unroll
        for (int mt = 0; mt < 4; ++mt) {
            const ushort* Arow = &P[pb][mt * 16 + ln][quad * 8];
            #pragma unroll
            for (int k0 = 0; k0 < 4; ++k0) {
                short8 af = *(const short8*)(Arow + k0 * 32);
                acc[mt] = __builtin_amdgcn_mfma_f32_16x16x32_bf16(af, bf[k0], acc[mt], 0, 0, 0);
            }
        }

        if (c + 1 < NCHUNK) scoresToLds(pb ^ 1);     // consume loads after MFMA issued
        __syncthreads();
        pb ^= 1;
    }

    // partial den: reduce across the 32-lane half (lanes of one rh share rows)
    #pragma unroll
    for (int rr = 0; rr < 8; ++rr) {
        float d = den[rr];
        #pragma unroll
        for (int off = 16; off; off >>= 1) d += __shfl_xor(d, off, 64);
        if (jg == 0)
            pden[(size_t)slice * NN + row0 + rbase + rh * 8 + rr] = d;
    }

    // partial num: D[m = quad*4 + r][n = ln] per m-tile (verified C/D layout)
    #pragma unroll
    for (int mt = 0; mt < 4; ++mt) {
        #pragma unroll
        for (int r = 0; r < 4; ++r) {
            const int i = mt * 16 + quad * 4 + r;
            pnum[((size_t)slice * NN + row0 + i) * FOUT + wv * 16 + ln] = acc[mt][r];
        }
    }
}

// K3: combine SPLIT partials, normalize, ELU. grid NN*FOUT/256.
__global__ __launch_bounds__(256) void gat_combine(const float* __restrict__ pnum,
                                                   const float* __restrict__ pden,
                                                   float* __restrict__ out) {
    const int idx = blockIdx.x * 256 + threadIdx.x;
    const int row = idx >> 6;
    float num = 0.f, den = 0.f;
    #pragma unroll
    for (int s = 0; s < SPLIT; ++s) {
        num += pnum[(size_t)s * NN * FOUT + idx];
        den += pden[(size_t)s * NN + row];
    }
    float o = num / den;
    o = (o > 0.f) ? o : (__expf(o) - 1.f);
    out[idx] = o;
}

extern "C" void kernel_launch(void* const* d_in, const int* in_sizes, int n_in,
                              void* d_out, int out_size, void* d_ws, size_t ws_size,
                              hipStream_t stream) {
    const float* x   = (const float*)d_in[0];   // [N, FIN]
    const int*   adj = (const int*)  d_in[1];   // [N, N]
    const float* W   = (const float*)d_in[2];   // [FIN, FOUT]
    const float* a   = (const float*)d_in[3];   // [2*FOUT, 1]
    float* out = (float*)d_out;                 // [N, FOUT]

    // ws: WhT bf16 [64][8192] (1MB) | Wh1 f32 [N] | Wh2 f32 [N]
    //   | pnum f32 [SPLIT][N][FOUT] (16MB) | pden f32 [SPLIT][N] (256KB)
    ushort* WhT = (ushort*)d_ws;
    float* Wh1 = (float*)(WhT + (size_t)FOUT * NN);
    float* Wh2 = Wh1 + NN;
    float* pnum = Wh2 + NN;
    float* pden = pnum + (size_t)SPLIT * NN * FOUT;

    gat_proj<<<NN / 32, 256, 0, stream>>>(x, W, a, WhT, Wh1, Wh2);
    gat_attn_part<<<(NN / BM) * SPLIT, 256, 0, stream>>>(adj, WhT, Wh1, Wh2, pnum, pden);
    gat_combine<<<NN * FOUT / 256, 256, 0, stream>>>(pnum, pden, out);
}